// Round 3
// baseline (160.621 us; speedup 1.0000x reference)
//
#include <hip/hip_runtime.h>

// KruskalLinearLayer — FUSED, ONE ROW PER WAVE, VGPR-pinned.
//   y[n,abc] = sum_r g0[a,r]g1[b,r]g2[c,r] * s[n,r] + bias[abc]
//   s[n,r]   = sum_{d,e,f} g3[d,r]g4[e,r]g5[f,r] * x[n,def]
//   g_m = f_m @ c_m  (16x8 @ 8x16)
//
// R7 post-mortem: launch_bounds(256,4) let the compiler squeeze to the
// NEXT tier (VGPR=64, 8 waves/SIMD) — w1[16] can't fit in 64 regs, so it
// rematerialized the weights from LDS inside the d-loop (229K bank
// conflicts, latency-bound, 45 us > R1's 38 us). The grid only supplies
// 16 waves/CU, so >4 waves/SIMD is pure loss.
// R8: amdgpu_waves_per_eu(4,4) pins the tier — compiler targets 128 VGPR
// and keeps w1 RESIDENT. Freed budget spent on d-loop unroll 4 (2x MLP:
// 4 outstanding 1KB loads/wave). Peak live ~120 regs: w1(64)+s(16)+
// 4*xd(16)+misc. Phase boundary sched_barrier + register reuse of
// w1->wb kept from R7 (that part worked).

typedef float f32x4 __attribute__((ext_vector_type(4)));

#define WPB 4   // waves per block

__global__ __launch_bounds__(256)
__attribute__((amdgpu_waves_per_eu(4, 4)))
void kruskal_fused(const float* __restrict__ x,
                   const float* __restrict__ c0, const float* __restrict__ c1,
                   const float* __restrict__ c2, const float* __restrict__ c3,
                   const float* __restrict__ c4, const float* __restrict__ c5,
                   const float* __restrict__ f0, const float* __restrict__ f1,
                   const float* __restrict__ f2, const float* __restrict__ f3,
                   const float* __restrict__ f4, const float* __restrict__ f5,
                   const float* __restrict__ bias,
                   float* __restrict__ out, int N)
{
    __shared__ __align__(16) float g3t[256];  // [d][r]  (uniform f32x4 reads per d)
    __shared__ __align__(16) float g4t[256];  // [r][e]
    __shared__ __align__(16) float g5t[256];  // [r][f]
    __shared__ __align__(16) float g0c[256];  // [a][r]  (uniform f32x4 reads per chunk)
    __shared__ __align__(16) float g1t[256];  // [r][b]
    __shared__ __align__(16) float g2t[256];  // [r][c]
    __shared__ __align__(16) float bsh[4096]; // staged bias (16 KB)

    const int tid = threadIdx.x;
    {
        const int i = tid >> 4, r = tid & 15;
        float a0 = 0.f, a1 = 0.f, a2 = 0.f, a3 = 0.f, a4 = 0.f, a5 = 0.f;
#pragma unroll
        for (int k = 0; k < 8; ++k) {
            a0 += f0[i * 8 + k] * c0[k * 16 + r];
            a1 += f1[i * 8 + k] * c1[k * 16 + r];
            a2 += f2[i * 8 + k] * c2[k * 16 + r];
            a3 += f3[i * 8 + k] * c3[k * 16 + r];
            a4 += f4[i * 8 + k] * c4[k * 16 + r];
            a5 += f5[i * 8 + k] * c5[k * 16 + r];
        }
        g0c[i * 16 + r] = a0;   // [a][r]
        g1t[r * 16 + i] = a1;   // [r][b]
        g2t[r * 16 + i] = a2;   // [r][c]
        g3t[i * 16 + r] = a3;   // [d][r]
        g4t[r * 16 + i] = a4;   // [r][e]
        g5t[r * 16 + i] = a5;   // [r][f]
    }
    {   // stage bias: 1024 f32x4, 256 threads x 4, coalesced
        const f32x4* b4 = (const f32x4*)bias;
        f32x4* bs4 = (f32x4*)bsh;
#pragma unroll
        for (int j = 0; j < 4; ++j) bs4[j * 256 + tid] = b4[j * 256 + tid];
    }
    __syncthreads();

    const int lane = tid & 63, waveId = tid >> 6;
    const int eb  = lane >> 2;         // e (phase1) / b (phase2)
    const int fcb = (lane & 3) * 4;    // f base     / c base

    const int n = blockIdx.x * WPB + waveId;   // ONE row per wave
    if (n >= N) return;
    const float* xn = x + (size_t)n * 4096;

    // ---- phase-1 lane weights (resident; DIE after phase 1) ----
    f32x4 w1[16];
#pragma unroll
    for (int r = 0; r < 16; ++r)
        w1[r] = (*(const f32x4*)&g5t[r * 16 + fcb]) * g4t[r * 16 + eb];

    // ---- phase 1: s[r] = sum_def g3 g4 g5 x ----
    float s[16];
#pragma unroll
    for (int r = 0; r < 16; ++r) s[r] = 0.f;

    // unroll 4: 4 outstanding 1KB loads per wave (2x R7's MLP); still
    // forbids the full-16 hoist (the R2/R4 spill trigger).
#pragma unroll 4
    for (int d = 0; d < 16; ++d) {
        const f32x4 xd = __builtin_nontemporal_load(
            (const f32x4*)(xn + d * 256 + lane * 4));
#pragma unroll
        for (int rq = 0; rq < 4; ++rq) {
            const f32x4 g3q = *(const f32x4*)&g3t[d * 16 + rq * 4]; // uniform
#pragma unroll
            for (int rr = 0; rr < 4; ++rr) {
                const int r = rq * 4 + rr;
                const float p = w1[r].x * xd.x + w1[r].y * xd.y
                              + w1[r].z * xd.z + w1[r].w * xd.w;
                s[r] += g3q[rr] * p;
            }
        }
    }

    // wave-wide allreduce of each s[r] (every lane needs all 16)
#pragma unroll
    for (int r = 0; r < 16; ++r) {
        float v = s[r];
        v += __shfl_xor(v, 1, 64);
        v += __shfl_xor(v, 2, 64);
        v += __shfl_xor(v, 4, 64);
        v += __shfl_xor(v, 8, 64);
        v += __shfl_xor(v, 16, 64);
        v += __shfl_xor(v, 32, 64);
        s[r] = v;
    }

    // Hard phase boundary: forbid hoisting wb's LDS reads into phase 1
    // (that would make w1 and wb simultaneously live -> over 128 VGPR).
    __builtin_amdgcn_sched_barrier(0);

    // ---- phase-2 lane weights (reuse w1's registers via liveness) ----
    f32x4 wb[16];
#pragma unroll
    for (int r = 0; r < 16; ++r)
        wb[r] = (*(const f32x4*)&g2t[r * 16 + fcb]) * g1t[r * 16 + eb];

    // ---- phase 2: all 16 output chunks of this row ----
    float* on = out + (size_t)n * 4096;
#pragma unroll 2
    for (int a = 0; a < 16; ++a) {
        f32x4 acc = *(const f32x4*)&bsh[a * 256 + lane * 4];
#pragma unroll
        for (int rq = 0; rq < 4; ++rq) {
            const f32x4 g0q = *(const f32x4*)&g0c[a * 16 + rq * 4]; // uniform
#pragma unroll
            for (int rr = 0; rr < 4; ++rr) {
                const int r = rq * 4 + rr;
                acc += (s[r] * g0q[rr]) * wb[r];
            }
        }
        __builtin_nontemporal_store(
            acc, (f32x4*)(on + a * 256 + lane * 4));
    }
}

extern "C" void kernel_launch(void* const* d_in, const int* in_sizes, int n_in,
                              void* d_out, int out_size, void* d_ws, size_t ws_size,
                              hipStream_t stream) {
    const float* x  = (const float*)d_in[0];
    const float* c0 = (const float*)d_in[1];
    const float* c1 = (const float*)d_in[2];
    const float* c2 = (const float*)d_in[3];
    const float* c3 = (const float*)d_in[4];
    const float* c4 = (const float*)d_in[5];
    const float* c5 = (const float*)d_in[6];
    const float* f0 = (const float*)d_in[7];
    const float* f1 = (const float*)d_in[8];
    const float* f2 = (const float*)d_in[9];
    const float* f3 = (const float*)d_in[10];
    const float* f4 = (const float*)d_in[11];
    const float* f5 = (const float*)d_in[12];
    const float* bias = (const float*)d_in[13];
    float* out = (float*)d_out;
    (void)d_ws; (void)ws_size;

    const int N = in_sizes[0] / 4096;
    const int blocks = (N + WPB - 1) / WPB;   // one row per wave

    kruskal_fused<<<dim3(blocks), dim3(256), 0, stream>>>(
        x, c0, c1, c2, c3, c4, c5, f0, f1, f2, f3, f4, f5, bias, out, N);
}

// Round 4
// 148.731 us; speedup vs baseline: 1.0799x; 1.0799x over previous
//
#include <hip/hip_runtime.h>

// KruskalLinearLayer — FUSED, ONE ROW PER WAVE, weights pinned via asm.
//   y[n,abc] = sum_r g0[a,r]g1[b,r]g2[c,r] * s[n,r] + bias[abc]
//   s[n,r]   = sum_{d,e,f} g3[d,r]g4[e,r]g5[f,r] * x[n,def]
//   g_m = f_m @ c_m  (16x8 @ 8x16)
//
// R8 post-mortem: amdgpu_waves_per_eu(4,4) did NOT stop the allocator
// from choosing VGPR=64 — it rematerialized w1/wb from LDS inside the
// loops (attributes can't forbid remat). And the 64-reg tier's 8
// waves/SIMD is unreachable anyway: one-row-per-wave = 4096 waves =
// 16/CU = 4/SIMD from the GRID. So we paid a dependent LDS read before
// every FMA cluster and got nothing.
// R9: empty `asm volatile("" : "+v"(vec))` after computing each weight
// makes the value OPAQUE — the compiler cannot rematerialize an asm
// result, so w1/wb must stay VGPR-resident (64 pinned + ~50 working ≈
// 110-125 regs → the 4-waves/SIMD tier the grid actually supplies).
// R7's liveness split retained: w1 dies at the phase boundary
// (sched_barrier), wb reuses its registers. unroll 4 = 4 outstanding
// 1KB loads/wave.

typedef float f32x4 __attribute__((ext_vector_type(4)));

#define WPB 4   // waves per block

__global__ __launch_bounds__(256, 2)
void kruskal_fused(const float* __restrict__ x,
                   const float* __restrict__ c0, const float* __restrict__ c1,
                   const float* __restrict__ c2, const float* __restrict__ c3,
                   const float* __restrict__ c4, const float* __restrict__ c5,
                   const float* __restrict__ f0, const float* __restrict__ f1,
                   const float* __restrict__ f2, const float* __restrict__ f3,
                   const float* __restrict__ f4, const float* __restrict__ f5,
                   const float* __restrict__ bias,
                   float* __restrict__ out, int N)
{
    __shared__ __align__(16) float g3t[256];  // [d][r]  (uniform f32x4 reads per d)
    __shared__ __align__(16) float g4t[256];  // [r][e]
    __shared__ __align__(16) float g5t[256];  // [r][f]
    __shared__ __align__(16) float g0c[256];  // [a][r]  (uniform f32x4 reads per chunk)
    __shared__ __align__(16) float g1t[256];  // [r][b]
    __shared__ __align__(16) float g2t[256];  // [r][c]
    __shared__ __align__(16) float bsh[4096]; // staged bias (16 KB)

    const int tid = threadIdx.x;
    {
        const int i = tid >> 4, r = tid & 15;
        float a0 = 0.f, a1 = 0.f, a2 = 0.f, a3 = 0.f, a4 = 0.f, a5 = 0.f;
#pragma unroll
        for (int k = 0; k < 8; ++k) {
            a0 += f0[i * 8 + k] * c0[k * 16 + r];
            a1 += f1[i * 8 + k] * c1[k * 16 + r];
            a2 += f2[i * 8 + k] * c2[k * 16 + r];
            a3 += f3[i * 8 + k] * c3[k * 16 + r];
            a4 += f4[i * 8 + k] * c4[k * 16 + r];
            a5 += f5[i * 8 + k] * c5[k * 16 + r];
        }
        g0c[i * 16 + r] = a0;   // [a][r]
        g1t[r * 16 + i] = a1;   // [r][b]
        g2t[r * 16 + i] = a2;   // [r][c]
        g3t[i * 16 + r] = a3;   // [d][r]
        g4t[r * 16 + i] = a4;   // [r][e]
        g5t[r * 16 + i] = a5;   // [r][f]
    }
    {   // stage bias: 1024 f32x4, 256 threads x 4, coalesced
        const f32x4* b4 = (const f32x4*)bias;
        f32x4* bs4 = (f32x4*)bsh;
#pragma unroll
        for (int j = 0; j < 4; ++j) bs4[j * 256 + tid] = b4[j * 256 + tid];
    }
    __syncthreads();

    const int lane = tid & 63, waveId = tid >> 6;
    const int eb  = lane >> 2;         // e (phase1) / b (phase2)
    const int fcb = (lane & 3) * 4;    // f base     / c base

    const int n = blockIdx.x * WPB + waveId;   // ONE row per wave
    if (n >= N) return;
    const float* xn = x + (size_t)n * 4096;

    // ---- phase-1 lane weights: computed once, PINNED in VGPRs ----
    // The empty asm makes each w1[r] opaque: the compiler cannot
    // rematerialize it from LDS (the R7/R8 failure mode).
    f32x4 w1[16];
#pragma unroll
    for (int r = 0; r < 16; ++r) {
        w1[r] = (*(const f32x4*)&g5t[r * 16 + fcb]) * g4t[r * 16 + eb];
        asm volatile("" : "+v"(w1[r]));
    }

    // ---- phase 1: s[r] = sum_def g3 g4 g5 x ----
    float s[16];
#pragma unroll
    for (int r = 0; r < 16; ++r) s[r] = 0.f;

    // unroll 4: 4 outstanding 1KB loads per wave; still forbids the
    // full-16 hoist (the R2/R4 spill trigger).
#pragma unroll 4
    for (int d = 0; d < 16; ++d) {
        const f32x4 xd = __builtin_nontemporal_load(
            (const f32x4*)(xn + d * 256 + lane * 4));
#pragma unroll
        for (int rq = 0; rq < 4; ++rq) {
            const f32x4 g3q = *(const f32x4*)&g3t[d * 16 + rq * 4]; // uniform
#pragma unroll
            for (int rr = 0; rr < 4; ++rr) {
                const int r = rq * 4 + rr;
                const float p = w1[r].x * xd.x + w1[r].y * xd.y
                              + w1[r].z * xd.z + w1[r].w * xd.w;
                s[r] += g3q[rr] * p;
            }
        }
    }

    // wave-wide allreduce of each s[r] (every lane needs all 16)
#pragma unroll
    for (int r = 0; r < 16; ++r) {
        float v = s[r];
        v += __shfl_xor(v, 1, 64);
        v += __shfl_xor(v, 2, 64);
        v += __shfl_xor(v, 4, 64);
        v += __shfl_xor(v, 8, 64);
        v += __shfl_xor(v, 16, 64);
        v += __shfl_xor(v, 32, 64);
        s[r] = v;
    }

    // Hard phase boundary: w1 is dead past here; forbid hoisting wb's
    // LDS reads into phase 1 (would make w1+wb simultaneously live).
    __builtin_amdgcn_sched_barrier(0);

    // ---- phase-2 lane weights: pinned likewise; reuse w1's registers ----
    f32x4 wb[16];
#pragma unroll
    for (int r = 0; r < 16; ++r) {
        wb[r] = (*(const f32x4*)&g2t[r * 16 + fcb]) * g1t[r * 16 + eb];
        asm volatile("" : "+v"(wb[r]));
    }

    // ---- phase 2: all 16 output chunks of this row ----
    float* on = out + (size_t)n * 4096;
#pragma unroll 2
    for (int a = 0; a < 16; ++a) {
        f32x4 acc = *(const f32x4*)&bsh[a * 256 + lane * 4];
#pragma unroll
        for (int rq = 0; rq < 4; ++rq) {
            const f32x4 g0q = *(const f32x4*)&g0c[a * 16 + rq * 4]; // uniform
#pragma unroll
            for (int rr = 0; rr < 4; ++rr) {
                const int r = rq * 4 + rr;
                acc += (s[r] * g0q[rr]) * wb[r];
            }
        }
        __builtin_nontemporal_store(
            acc, (f32x4*)(on + a * 256 + lane * 4));
    }
}

extern "C" void kernel_launch(void* const* d_in, const int* in_sizes, int n_in,
                              void* d_out, int out_size, void* d_ws, size_t ws_size,
                              hipStream_t stream) {
    const float* x  = (const float*)d_in[0];
    const float* c0 = (const float*)d_in[1];
    const float* c1 = (const float*)d_in[2];
    const float* c2 = (const float*)d_in[3];
    const float* c3 = (const float*)d_in[4];
    const float* c4 = (const float*)d_in[5];
    const float* c5 = (const float*)d_in[6];
    const float* f0 = (const float*)d_in[7];
    const float* f1 = (const float*)d_in[8];
    const float* f2 = (const float*)d_in[9];
    const float* f3 = (const float*)d_in[10];
    const float* f4 = (const float*)d_in[11];
    const float* f5 = (const float*)d_in[12];
    const float* bias = (const float*)d_in[13];
    float* out = (float*)d_out;
    (void)d_ws; (void)ws_size;

    const int N = in_sizes[0] / 4096;
    const int blocks = (N + WPB - 1) / WPB;   // one row per wave

    kruskal_fused<<<dim3(blocks), dim3(256), 0, stream>>>(
        x, c0, c1, c2, c3, c4, c5, f0, f1, f2, f3, f4, f5, bias, out, N);
}

// Round 5
// 146.782 us; speedup vs baseline: 1.0943x; 1.0133x over previous
//
#include <hip/hip_runtime.h>

// KruskalLinearLayer — FUSED, ONE ROW PER WAVE, pinned weights +
// DOUBLE-BUFFERED x load pipeline.
//   y[n,abc] = sum_r g0[a,r]g1[b,r]g2[c,r] * s[n,r] + bias[abc]
//   s[n,r]   = sum_{d,e,f} g3[d,r]g4[e,r]g5[f,r] * x[n,def]
//   g_m = f_m @ c_m  (16x8 @ 8x16)
//
// R9 post-mortem: asm pin ("+v") beat the remat (R8's VGPR=64 trap);
// kernel ~36us, best so far. Still above the 20us traffic floor
// (123MB @ 6.3TB/s): VALU total is only ~9us, so the gap is LATENCY —
// with `unroll 4` the in-order wave issues 4 loads, waits, computes,
// and only then issues the next 4 (xd anti-dependency serializes).
// R10: explicit ping-pong xa/xb batches — batch i+1's loads are issued
// BEFORE batch i's compute, so 4-8KB/wave stays in flight under the
// 640cy compute. Peak live: xa+xb(32) + w1(64) + s(16) + addr ≈ 120
// ≤ 128 → still 4 waves/SIMD. Pins + w1→wb liveness split kept (R9).

typedef float f32x4 __attribute__((ext_vector_type(4)));

#define WPB 4   // waves per block

__global__ __launch_bounds__(256, 2)
void kruskal_fused(const float* __restrict__ x,
                   const float* __restrict__ c0, const float* __restrict__ c1,
                   const float* __restrict__ c2, const float* __restrict__ c3,
                   const float* __restrict__ c4, const float* __restrict__ c5,
                   const float* __restrict__ f0, const float* __restrict__ f1,
                   const float* __restrict__ f2, const float* __restrict__ f3,
                   const float* __restrict__ f4, const float* __restrict__ f5,
                   const float* __restrict__ bias,
                   float* __restrict__ out, int N)
{
    __shared__ __align__(16) float g3t[256];  // [d][r]  (uniform f32x4 reads per d)
    __shared__ __align__(16) float g4t[256];  // [r][e]
    __shared__ __align__(16) float g5t[256];  // [r][f]
    __shared__ __align__(16) float g0c[256];  // [a][r]  (uniform f32x4 reads per chunk)
    __shared__ __align__(16) float g1t[256];  // [r][b]
    __shared__ __align__(16) float g2t[256];  // [r][c]
    __shared__ __align__(16) float bsh[4096]; // staged bias (16 KB)

    const int tid = threadIdx.x;
    {
        const int i = tid >> 4, r = tid & 15;
        float a0 = 0.f, a1 = 0.f, a2 = 0.f, a3 = 0.f, a4 = 0.f, a5 = 0.f;
#pragma unroll
        for (int k = 0; k < 8; ++k) {
            a0 += f0[i * 8 + k] * c0[k * 16 + r];
            a1 += f1[i * 8 + k] * c1[k * 16 + r];
            a2 += f2[i * 8 + k] * c2[k * 16 + r];
            a3 += f3[i * 8 + k] * c3[k * 16 + r];
            a4 += f4[i * 8 + k] * c4[k * 16 + r];
            a5 += f5[i * 8 + k] * c5[k * 16 + r];
        }
        g0c[i * 16 + r] = a0;   // [a][r]
        g1t[r * 16 + i] = a1;   // [r][b]
        g2t[r * 16 + i] = a2;   // [r][c]
        g3t[i * 16 + r] = a3;   // [d][r]
        g4t[r * 16 + i] = a4;   // [r][e]
        g5t[r * 16 + i] = a5;   // [r][f]
    }
    {   // stage bias: 1024 f32x4, 256 threads x 4, coalesced
        const f32x4* b4 = (const f32x4*)bias;
        f32x4* bs4 = (f32x4*)bsh;
#pragma unroll
        for (int j = 0; j < 4; ++j) bs4[j * 256 + tid] = b4[j * 256 + tid];
    }
    __syncthreads();

    const int lane = tid & 63, waveId = tid >> 6;
    const int eb  = lane >> 2;         // e (phase1) / b (phase2)
    const int fcb = (lane & 3) * 4;    // f base     / c base

    const int n = blockIdx.x * WPB + waveId;   // ONE row per wave
    if (n >= N) return;
    const float* xn = x + (size_t)n * 4096 + lane * 4;

    // ---- phase-1 lane weights: computed once, PINNED in VGPRs ----
    // The empty asm makes each w1[r] opaque: no remat from LDS (R7/R8 trap).
    f32x4 w1[16];
#pragma unroll
    for (int r = 0; r < 16; ++r) {
        w1[r] = (*(const f32x4*)&g5t[r * 16 + fcb]) * g4t[r * 16 + eb];
        asm volatile("" : "+v"(w1[r]));
    }

    // ---- phase 1: s[r] = sum_def g3 g4 g5 x ----
    float s[16];
#pragma unroll
    for (int r = 0; r < 16; ++r) s[r] = 0.f;

#define LOAD4(v, dbase)                                                       \
    v##0 = __builtin_nontemporal_load((const f32x4*)(xn + ((dbase) + 0) * 256)); \
    v##1 = __builtin_nontemporal_load((const f32x4*)(xn + ((dbase) + 1) * 256)); \
    v##2 = __builtin_nontemporal_load((const f32x4*)(xn + ((dbase) + 2) * 256)); \
    v##3 = __builtin_nontemporal_load((const f32x4*)(xn + ((dbase) + 3) * 256));

#define COMP1(xv, d)                                                          \
    {                                                                         \
        _Pragma("unroll")                                                     \
        for (int rq = 0; rq < 4; ++rq) {                                      \
            const f32x4 g3q = *(const f32x4*)&g3t[(d) * 16 + rq * 4];         \
            _Pragma("unroll")                                                 \
            for (int rr = 0; rr < 4; ++rr) {                                  \
                const int r = rq * 4 + rr;                                    \
                const float p = w1[r].x * xv.x + w1[r].y * xv.y               \
                              + w1[r].z * xv.z + w1[r].w * xv.w;              \
                s[r] += g3q[rr] * p;                                          \
            }                                                                 \
        }                                                                     \
    }

#define COMP4(v, dbase)                                                       \
    COMP1(v##0, (dbase) + 0) COMP1(v##1, (dbase) + 1)                         \
    COMP1(v##2, (dbase) + 2) COMP1(v##3, (dbase) + 3)

    {
        // ping-pong double buffer: batch i+1's loads are in flight while
        // batch i computes. Peak live xa+xb = 32 regs.
        f32x4 xa0, xa1, xa2, xa3, xb0, xb1, xb2, xb3;
        LOAD4(xa, 0)
        LOAD4(xb, 4)
        COMP4(xa, 0)          // waits only on xa; xb stays in flight
        LOAD4(xa, 8)          // WAR on xa resolved; issues under xb's compute
        COMP4(xb, 4)
        LOAD4(xb, 12)
        COMP4(xa, 8)
        COMP4(xb, 12)
    }
#undef LOAD4
#undef COMP1
#undef COMP4

    // wave-wide allreduce of each s[r] (every lane needs all 16)
#pragma unroll
    for (int r = 0; r < 16; ++r) {
        float v = s[r];
        v += __shfl_xor(v, 1, 64);
        v += __shfl_xor(v, 2, 64);
        v += __shfl_xor(v, 4, 64);
        v += __shfl_xor(v, 8, 64);
        v += __shfl_xor(v, 16, 64);
        v += __shfl_xor(v, 32, 64);
        s[r] = v;
    }

    // Hard phase boundary: w1 is dead past here; forbid hoisting wb's
    // LDS reads into phase 1 (would make w1+wb simultaneously live).
    __builtin_amdgcn_sched_barrier(0);

    // ---- phase-2 lane weights: pinned likewise; reuse w1's registers ----
    f32x4 wb[16];
#pragma unroll
    for (int r = 0; r < 16; ++r) {
        wb[r] = (*(const f32x4*)&g2t[r * 16 + fcb]) * g1t[r * 16 + eb];
        asm volatile("" : "+v"(wb[r]));
    }

    // ---- phase 2: all 16 output chunks of this row ----
    float* on = out + (size_t)n * 4096;
#pragma unroll 2
    for (int a = 0; a < 16; ++a) {
        f32x4 acc = *(const f32x4*)&bsh[a * 256 + lane * 4];
#pragma unroll
        for (int rq = 0; rq < 4; ++rq) {
            const f32x4 g0q = *(const f32x4*)&g0c[a * 16 + rq * 4]; // uniform
#pragma unroll
            for (int rr = 0; rr < 4; ++rr) {
                const int r = rq * 4 + rr;
                acc += (s[r] * g0q[rr]) * wb[r];
            }
        }
        __builtin_nontemporal_store(
            acc, (f32x4*)(on + a * 256 + lane * 4));
    }
}

extern "C" void kernel_launch(void* const* d_in, const int* in_sizes, int n_in,
                              void* d_out, int out_size, void* d_ws, size_t ws_size,
                              hipStream_t stream) {
    const float* x  = (const float*)d_in[0];
    const float* c0 = (const float*)d_in[1];
    const float* c1 = (const float*)d_in[2];
    const float* c2 = (const float*)d_in[3];
    const float* c3 = (const float*)d_in[4];
    const float* c4 = (const float*)d_in[5];
    const float* c5 = (const float*)d_in[6];
    const float* f0 = (const float*)d_in[7];
    const float* f1 = (const float*)d_in[8];
    const float* f2 = (const float*)d_in[9];
    const float* f3 = (const float*)d_in[10];
    const float* f4 = (const float*)d_in[11];
    const float* f5 = (const float*)d_in[12];
    const float* bias = (const float*)d_in[13];
    float* out = (float*)d_out;
    (void)d_ws; (void)ws_size;

    const int N = in_sizes[0] / 4096;
    const int blocks = (N + WPB - 1) / WPB;   // one row per wave

    kruskal_fused<<<dim3(blocks), dim3(256), 0, stream>>>(
        x, c0, c1, c2, c3, c4, c5, f0, f1, f2, f3, f4, f5, bias, out, N);
}